// Round 12
// baseline (820.560 us; speedup 1.0000x reference)
//
#include <hip/hip_runtime.h>

#define NN 50000
#define NE 800000
#define FF 128
#define KF 8
#define DD 16
#define GG 512
#define BN_EPS 1e-5f
#define NB 196   // ceil(NN/256)
#define KSTR 264 // padded k-block stride for block-diag weights

using s8v = __attribute__((ext_vector_type(8))) short;
using f4v = __attribute__((ext_vector_type(4))) float;

// ---------------- CSR build ----------------
__global__ void k_deg(const int* __restrict__ dst, int* __restrict__ deg) {
    int e = blockIdx.x * 256 + threadIdx.x;
    if (e < NE) atomicAdd(&deg[dst[e]], 1);
}

__global__ __launch_bounds__(256) void k_bsum(const int* __restrict__ deg, int* __restrict__ bsum) {
    int idx = blockIdx.x * 256 + threadIdx.x;
    int v = (idx < NN) ? deg[idx] : 0;
#pragma unroll
    for (int off = 32; off; off >>= 1) v += __shfl_down(v, off, 64);
    __shared__ int ws[4];
    if ((threadIdx.x & 63) == 0) ws[threadIdx.x >> 6] = v;
    __syncthreads();
    if (threadIdx.x == 0) bsum[blockIdx.x] = ws[0] + ws[1] + ws[2] + ws[3];
}

__global__ __launch_bounds__(256) void k_bscan(const int* __restrict__ bsum, int* __restrict__ boffs) {
    __shared__ int s[256];
    int tid = threadIdx.x;
    int v = (tid < NB) ? bsum[tid] : 0;
    s[tid] = v;
    __syncthreads();
    for (int off = 1; off < 256; off <<= 1) {
        int t = (tid >= off) ? s[tid - off] : 0;
        __syncthreads();
        s[tid] += t;
        __syncthreads();
    }
    if (tid < NB) boffs[tid] = s[tid] - v;  // exclusive
}

__global__ __launch_bounds__(256) void k_offs(const int* __restrict__ deg,
                                              const int* __restrict__ boffs,
                                              int* __restrict__ offs) {
    __shared__ int s[256];
    int tid = threadIdx.x;
    int idx = blockIdx.x * 256 + tid;
    int v = (idx < NN) ? deg[idx] : 0;
    s[tid] = v;
    __syncthreads();
    for (int off = 1; off < 256; off <<= 1) {
        int t = (tid >= off) ? s[tid - off] : 0;
        __syncthreads();
        s[tid] += t;
        __syncthreads();
    }
    int incl = s[tid];
    if (idx < NN) offs[idx] = boffs[blockIdx.x] + incl - v;
    if (idx == NN - 1) offs[NN] = boffs[blockIdx.x] + incl;
}

__global__ void k_fill(const int* __restrict__ src, const int* __restrict__ dst,
                       const int* __restrict__ offs, int* __restrict__ cnt,
                       int* __restrict__ csr) {
    int e = blockIdx.x * 256 + threadIdx.x;
    if (e < NE) {
        int d = dst[e];
        int p = atomicAdd(&cnt[d], 1);
        csr[offs[d] + p] = src[e];
    }
}

// ---------------- helpers ----------------
__device__ __forceinline__ void bn_coefs(const float* st, const float* g, const float* be,
                                         int lane, float4& a4, float4& b4) {
    const float inv_n = 1.0f / (float)NN;
    float av[4], bv[4];
#pragma unroll
    for (int t = 0; t < 4; t++) {
        int c = lane * 4 + t;
        float mu = st[c] * inv_n;
        float var = st[FF + c] * inv_n - mu * mu;
        float a = g[c] * rsqrtf(var + BN_EPS);
        av[t] = a;
        bv[t] = be[c] - mu * a;
    }
    a4 = make_float4(av[0], av[1], av[2], av[3]);
    b4 = make_float4(bv[0], bv[1], bv[2], bv[3]);
}

// split fp32 -> bf16 hi + bf16 lo (round-to-nearest-even both)
__device__ __forceinline__ void f2bf2(float v, unsigned short& hi, unsigned short& lo) {
    unsigned u = __float_as_uint(v);
    unsigned r = u + 0x7fffu + ((u >> 16) & 1u);
    hi = (unsigned short)(r >> 16);
    float hf = __uint_as_float(((unsigned)hi) << 16);
    float lf = v - hf;
    unsigned u2 = __float_as_uint(lf);
    unsigned r2 = u2 + 0x7fffu + ((u2 >> 16) & 1u);
    lo = (unsigned short)(r2 >> 16);
}

// ---------------- weight prep: fp32 [l][k][n] -> bf16 hi/lo transposed [n][k] -------
__global__ __launch_bounds__(256) void k_wprep(const float* __restrict__ W1,
                                               const float* __restrict__ W2,
                                               unsigned short* __restrict__ out) {
    int idx = blockIdx.x * 256 + threadIdx.x;  // over 3*2*16384
    if (idx >= 3 * 2 * 16384) return;
    int l = idx / (2 * 16384);
    int rem = idx % (2 * 16384);
    int mat = rem >> 14;
    int e = rem & 16383;
    int n = e >> 7, k = e & 127;
    const float* W = (mat == 0) ? (W1 + (size_t)l * 16384) : (W2 + (size_t)l * 16384);
    float v = W[k * 128 + n];
    unsigned short hi, lo;
    f2bf2(v, hi, lo);
    unsigned short* o = out + (size_t)((l * 2 + mat) * 2) * 16384;
    o[n * 128 + k] = hi;
    o[16384 + n * 128 + k] = lo;
}

// ---------------- weight prep for h0: Wcat^T (slot 6) + blockdiag(W2)^T (slot 7) ---
__global__ __launch_bounds__(256) void k_wprep_h0(const float* __restrict__ W1,  // [K,F,d]
                                                  const float* __restrict__ W2,  // [K,d,d]
                                                  unsigned short* __restrict__ out) {
    int idx = blockIdx.x * 256 + threadIdx.x;  // over 2*16384
    if (idx >= 2 * 16384) return;
    int mat = idx >> 14;
    int e = idx & 16383;
    int n = e >> 7, k = e & 127;  // n = output col, k = input feature
    float v;
    if (mat == 0) {
        // Wcat[k][n] = W1[n/16][k][n%16]
        v = W1[(n >> 4) * (FF * DD) + k * DD + (n & 15)];
    } else {
        // W2full[k][n] = (k/16==n/16) ? W2[n/16][k%16][n%16] : 0
        v = ((k >> 4) == (n >> 4)) ? W2[(n >> 4) * 256 + (k & 15) * DD + (n & 15)] : 0.f;
    }
    unsigned short hi, lo;
    f2bf2(v, hi, lo);
    unsigned short* o = out + (size_t)(6 + mat) * 32768;
    o[n * 128 + k] = hi;
    o[16384 + n * 128 + k] = lo;
}

// ---------------- XCD-sliced aggregation with fused BN(+relu) ----------------------
// blockIdx%8 = col-group g (XCD round-robin heuristic): each XCD gathers only cols
// [16g,16g+16) -> per-XCD X-slice 3.2 MB, L2-resident. Thread = (node, float4-col).
template <bool BN, bool RELU>
__global__ __launch_bounds__(256) void k_aggx(const float4* __restrict__ X,
                                              const int* __restrict__ offs,
                                              const int* __restrict__ csr,
                                              const float* __restrict__ st,
                                              const float* __restrict__ g,
                                              const float* __restrict__ be,
                                              float4* __restrict__ Z) {
    int gcol = blockIdx.x & 7;
    int tile = blockIdx.x >> 3;
    int n = tile * 64 + (threadIdx.x >> 2);
    int c4 = gcol * 4 + (threadIdx.x & 3);  // float4 column index (0..31)
    if (n >= NN) return;

    float4 a4 = make_float4(1.f, 1.f, 1.f, 1.f);
    float4 b4 = make_float4(0.f, 0.f, 0.f, 0.f);
    if (BN) bn_coefs(st, g, be, c4, a4, b4);

    auto apply = [&](float4 v) -> float4 {
        if (BN) {
            v.x = fmaf(v.x, a4.x, b4.x);
            v.y = fmaf(v.y, a4.y, b4.y);
            v.z = fmaf(v.z, a4.z, b4.z);
            v.w = fmaf(v.w, a4.w, b4.w);
        }
        if (RELU) {
            v.x = fmaxf(v.x, 0.f);
            v.y = fmaxf(v.y, 0.f);
            v.z = fmaxf(v.z, 0.f);
            v.w = fmaxf(v.w, 0.f);
        }
        return v;
    };
    auto add4 = [](float4& a, float4 b) {
        a.x += b.x; a.y += b.y; a.z += b.z; a.w += b.w;
    };

    float4 acc = apply(X[(size_t)n * 32 + c4]);
    int e0 = offs[n], e1 = offs[n + 1];
    int e = e0;
    for (; e + 8 <= e1; e += 8) {
        int s0 = csr[e], s1 = csr[e + 1], s2 = csr[e + 2], s3 = csr[e + 3];
        int s4 = csr[e + 4], s5 = csr[e + 5], s6 = csr[e + 6], s7 = csr[e + 7];
        float4 v0 = X[(size_t)s0 * 32 + c4];
        float4 v1 = X[(size_t)s1 * 32 + c4];
        float4 v2 = X[(size_t)s2 * 32 + c4];
        float4 v3 = X[(size_t)s3 * 32 + c4];
        float4 v4 = X[(size_t)s4 * 32 + c4];
        float4 v5 = X[(size_t)s5 * 32 + c4];
        float4 v6 = X[(size_t)s6 * 32 + c4];
        float4 v7 = X[(size_t)s7 * 32 + c4];
        v0 = apply(v0); v1 = apply(v1); v2 = apply(v2); v3 = apply(v3);
        v4 = apply(v4); v5 = apply(v5); v6 = apply(v6); v7 = apply(v7);
        add4(v0, v1); add4(v2, v3); add4(v4, v5); add4(v6, v7);
        add4(v0, v2); add4(v4, v6); add4(v0, v4); add4(acc, v0);
    }
    for (; e + 4 <= e1; e += 4) {
        int s0 = csr[e], s1 = csr[e + 1], s2 = csr[e + 2], s3 = csr[e + 3];
        float4 v0 = apply(X[(size_t)s0 * 32 + c4]);
        float4 v1 = apply(X[(size_t)s1 * 32 + c4]);
        float4 v2 = apply(X[(size_t)s2 * 32 + c4]);
        float4 v3 = apply(X[(size_t)s3 * 32 + c4]);
        add4(v0, v1); add4(v2, v3); add4(v0, v2); add4(acc, v0);
    }
    for (; e < e1; e++) {
        float4 v = apply(X[(size_t)csr[e] * 32 + c4]);
        add4(acc, v);
    }
    Z[(size_t)n * 32 + c4] = acc;
}

// ============ MFMA bf16x3 GEMM pair: C = relu(A@W1+b1)@W2 + b2, + stats ============
__global__ __launch_bounds__(256) void gemm_mfma(const float4* __restrict__ A,
                                                 const unsigned short* __restrict__ W1T,
                                                 const unsigned short* __restrict__ W2T,
                                                 const float* __restrict__ b1,
                                                 const float* __restrict__ b2,
                                                 float* __restrict__ C,
                                                 float* __restrict__ stout) {
    __shared__ __align__(16) unsigned short Abf[2 * 64 * 136];  // 34816 B
    __shared__ __align__(16) unsigned short Wch[2 * 128 * 40];  // 20480 B
    int tid = threadIdx.x;
    int row0 = blockIdx.x * 64;
    int w = tid >> 6, lane = tid & 63, quad = lane >> 4, lid = lane & 15;

    // stage A -> bf16 hi/lo (row-major)
#pragma unroll
    for (int i = 0; i < 8; i++) {
        int l = tid + i * 256;
        int r = l >> 5, q4 = l & 31;
        int gr = row0 + r;
        if (gr >= NN) gr = NN - 1;
        float4 v = A[(size_t)gr * 32 + q4];
        unsigned short h0, l0, h1, l1, h2, l2, h3, l3;
        f2bf2(v.x, h0, l0); f2bf2(v.y, h1, l1);
        f2bf2(v.z, h2, l2); f2bf2(v.w, h3, l3);
        *(ushort4*)&Abf[r * 136 + q4 * 4] = make_ushort4(h0, h1, h2, h3);
        *(ushort4*)&Abf[8704 + r * 136 + q4 * 4] = make_ushort4(l0, l1, l2, l3);
    }
    __syncthreads();

    f4v acc[8];
#pragma unroll
    for (int i = 0; i < 8; i++) acc[i] = 0;

    // ---- phase 1: z = relu(A@W1 + b1) ----
    for (int kc = 0; kc < 4; kc++) {
#pragma unroll
        for (int i = 0; i < 8; i++) {
            int l = tid + i * 256;
            int part = l >> 10, rem = l & 1023;
            int n = rem >> 3, kq = rem & 7;
            ushort4 v = *(const ushort4*)&W1T[(size_t)part * 16384 + n * 128 + kc * 32 + kq * 4];
            *(ushort4*)&Wch[part * 5120 + n * 40 + kq * 4] = v;
        }
        __syncthreads();
        s8v ah = *(const s8v*)&Abf[(w * 16 + lid) * 136 + kc * 32 + quad * 8];
        s8v al = *(const s8v*)&Abf[8704 + (w * 16 + lid) * 136 + kc * 32 + quad * 8];
#pragma unroll
        for (int n0 = 0; n0 < 8; n0++) {
            s8v bh = *(const s8v*)&Wch[(n0 * 16 + lid) * 40 + quad * 8];
            s8v bl = *(const s8v*)&Wch[5120 + (n0 * 16 + lid) * 40 + quad * 8];
            acc[n0] = __builtin_amdgcn_mfma_f32_16x16x32_bf16(ah, bh, acc[n0], 0, 0, 0);
            acc[n0] = __builtin_amdgcn_mfma_f32_16x16x32_bf16(al, bh, acc[n0], 0, 0, 0);
            acc[n0] = __builtin_amdgcn_mfma_f32_16x16x32_bf16(ah, bl, acc[n0], 0, 0, 0);
        }
        __syncthreads();
    }

    // z = relu(acc+b1) -> Abf bf16 hi/lo (this wave's rows; no extra barrier needed
    // before phase-2's kc=0 barrier)
#pragma unroll
    for (int n0 = 0; n0 < 8; n0++) {
        int c = n0 * 16 + lid;
        float bb = b1[c];
#pragma unroll
        for (int rr = 0; rr < 4; rr++) {
            int lr = w * 16 + quad * 4 + rr;
            float z = fmaxf(acc[n0][rr] + bb, 0.f);
            unsigned short h, lo2;
            f2bf2(z, h, lo2);
            Abf[lr * 136 + c] = h;
            Abf[8704 + lr * 136 + c] = lo2;
        }
        acc[n0] = 0;
    }

    // ---- phase 2: C = z@W2 + b2 ----
    for (int kc = 0; kc < 4; kc++) {
#pragma unroll
        for (int i = 0; i < 8; i++) {
            int l = tid + i * 256;
            int part = l >> 10, rem = l & 1023;
            int n = rem >> 3, kq = rem & 7;
            ushort4 v = *(const ushort4*)&W2T[(size_t)part * 16384 + n * 128 + kc * 32 + kq * 4];
            *(ushort4*)&Wch[part * 5120 + n * 40 + kq * 4] = v;
        }
        __syncthreads();
        s8v ah = *(const s8v*)&Abf[(w * 16 + lid) * 136 + kc * 32 + quad * 8];
        s8v al = *(const s8v*)&Abf[8704 + (w * 16 + lid) * 136 + kc * 32 + quad * 8];
#pragma unroll
        for (int n0 = 0; n0 < 8; n0++) {
            s8v bh = *(const s8v*)&Wch[(n0 * 16 + lid) * 40 + quad * 8];
            s8v bl = *(const s8v*)&Wch[5120 + (n0 * 16 + lid) * 40 + quad * 8];
            acc[n0] = __builtin_amdgcn_mfma_f32_16x16x32_bf16(ah, bh, acc[n0], 0, 0, 0);
            acc[n0] = __builtin_amdgcn_mfma_f32_16x16x32_bf16(al, bh, acc[n0], 0, 0, 0);
            acc[n0] = __builtin_amdgcn_mfma_f32_16x16x32_bf16(ah, bl, acc[n0], 0, 0, 0);
        }
        __syncthreads();
    }

    // ---- epilogue: bias, store, stats ----
    float* Sred = (float*)Wch;
#pragma unroll
    for (int n0 = 0; n0 < 8; n0++) {
        int c = n0 * 16 + lid;
        float bb = b2[c];
        float s = 0.f, q = 0.f;
#pragma unroll
        for (int rr = 0; rr < 4; rr++) {
            int grow = row0 + w * 16 + quad * 4 + rr;
            if (grow < NN) {
                float v = acc[n0][rr] + bb;
                C[(size_t)grow * 128 + c] = v;
                s += v;
                q += v * v;
            }
        }
        s += __shfl_xor(s, 16); s += __shfl_xor(s, 32);
        q += __shfl_xor(q, 16); q += __shfl_xor(q, 32);
        if (quad == 0) {
            Sred[w * 128 + c] = s;
            Sred[512 + w * 128 + c] = q;
        }
    }
    __syncthreads();
    if (tid < 128) {
        float s = Sred[tid] + Sred[128 + tid] + Sred[256 + tid] + Sred[384 + tid];
        float q = Sred[512 + tid] + Sred[640 + tid] + Sred[768 + tid] + Sred[896 + tid];
        atomicAdd(&stout[tid], s);
        atomicAdd(&stout[FF + tid], q);
    }
}

// ---------------- fused h1: agg(BN+relu on load) + double block-diag MLP -----------
__global__ __launch_bounds__(256) void k_aggbd(const float4* __restrict__ X,
                                               const int* __restrict__ offs,
                                               const int* __restrict__ csr,
                                               const float* __restrict__ st,
                                               const float* __restrict__ g,
                                               const float* __restrict__ be,
                                               const float* __restrict__ W1,
                                               const float4* __restrict__ b1,
                                               const float* __restrict__ W2,
                                               const float4* __restrict__ b2,
                                               float4* __restrict__ C) {
    __shared__ float As[8][128];
    __shared__ float Ts[8][128];
    __shared__ float Ws1[KF * KSTR];
    __shared__ float Ws2[KF * KSTR];
    int grp = threadIdx.x >> 5, lane = threadIdx.x & 31;
    int n = blockIdx.x * 8 + grp;

    for (int l = threadIdx.x; l < KF * 256; l += 256) {
        int k = l >> 8, r = l & 255;
        Ws1[k * KSTR + r] = W1[l];
        Ws2[k * KSTR + r] = W2[l];
    }

    float4 a4, b4;
    bn_coefs(st, g, be, lane, a4, b4);
    auto apply = [&](float4 v) -> float4 {
        v.x = fmaxf(fmaf(v.x, a4.x, b4.x), 0.f);
        v.y = fmaxf(fmaf(v.y, a4.y, b4.y), 0.f);
        v.z = fmaxf(fmaf(v.z, a4.z, b4.z), 0.f);
        v.w = fmaxf(fmaf(v.w, a4.w, b4.w), 0.f);
        return v;
    };
    auto add4 = [](float4& a, float4 b) {
        a.x += b.x; a.y += b.y; a.z += b.z; a.w += b.w;
    };

    float4 acc = apply(X[(size_t)n * 32 + lane]);
    int e0 = offs[n], e1 = offs[n + 1];
    int e = e0;
    for (; e + 8 <= e1; e += 8) {
        int s0 = csr[e], s1 = csr[e + 1], s2 = csr[e + 2], s3 = csr[e + 3];
        int s4 = csr[e + 4], s5 = csr[e + 5], s6 = csr[e + 6], s7 = csr[e + 7];
        float4 v0 = X[(size_t)s0 * 32 + lane];
        float4 v1 = X[(size_t)s1 * 32 + lane];
        float4 v2 = X[(size_t)s2 * 32 + lane];
        float4 v3 = X[(size_t)s3 * 32 + lane];
        float4 v4 = X[(size_t)s4 * 32 + lane];
        float4 v5 = X[(size_t)s5 * 32 + lane];
        float4 v6 = X[(size_t)s6 * 32 + lane];
        float4 v7 = X[(size_t)s7 * 32 + lane];
        v0 = apply(v0); v1 = apply(v1); v2 = apply(v2); v3 = apply(v3);
        v4 = apply(v4); v5 = apply(v5); v6 = apply(v6); v7 = apply(v7);
        add4(v0, v1); add4(v2, v3); add4(v4, v5); add4(v6, v7);
        add4(v0, v2); add4(v4, v6); add4(v0, v4); add4(acc, v0);
    }
    for (; e + 4 <= e1; e += 4) {
        int s0 = csr[e], s1 = csr[e + 1], s2 = csr[e + 2], s3 = csr[e + 3];
        float4 v0 = apply(X[(size_t)s0 * 32 + lane]);
        float4 v1 = apply(X[(size_t)s1 * 32 + lane]);
        float4 v2 = apply(X[(size_t)s2 * 32 + lane]);
        float4 v3 = apply(X[(size_t)s3 * 32 + lane]);
        add4(v0, v1); add4(v2, v3); add4(v0, v2); add4(acc, v0);
    }
    for (; e < e1; e++) {
        float4 v = apply(X[(size_t)csr[e] * 32 + lane]);
        add4(acc, v);
    }
    ((float4*)&As[grp][0])[lane] = acc;
    __syncthreads();

    int k = lane >> 2, jb = (lane & 3) * 4;
    float a[16];
    {
        const float4* As4 = (const float4*)&As[grp][k * 16];
        float4 a0 = As4[0], a1 = As4[1], a2 = As4[2], a3 = As4[3];
        a[0] = a0.x; a[1] = a0.y; a[2] = a0.z; a[3] = a0.w;
        a[4] = a1.x; a[5] = a1.y; a[6] = a1.z; a[7] = a1.w;
        a[8] = a2.x; a[9] = a2.y; a[10] = a2.z; a[11] = a2.w;
        a[12] = a3.x; a[13] = a3.y; a[14] = a3.z; a[15] = a3.w;
    }
    const float* wp1 = &Ws1[k * KSTR + jb];
    float4 t = b1[lane];
#pragma unroll
    for (int i = 0; i < 16; i++) {
        float4 wv = *(const float4*)&wp1[i * 16];
        t.x = fmaf(a[i], wv.x, t.x);
        t.y = fmaf(a[i], wv.y, t.y);
        t.z = fmaf(a[i], wv.z, t.z);
        t.w = fmaf(a[i], wv.w, t.w);
    }
    t.x = fmaxf(t.x, 0.f); t.y = fmaxf(t.y, 0.f);
    t.z = fmaxf(t.z, 0.f); t.w = fmaxf(t.w, 0.f);
    ((float4*)&Ts[grp][0])[lane] = t;
    __syncthreads();

    float b[16];
    {
        const float4* Ts4 = (const float4*)&Ts[grp][k * 16];
        float4 a0 = Ts4[0], a1 = Ts4[1], a2 = Ts4[2], a3 = Ts4[3];
        b[0] = a0.x; b[1] = a0.y; b[2] = a0.z; b[3] = a0.w;
        b[4] = a1.x; b[5] = a1.y; b[6] = a1.z; b[7] = a1.w;
        b[8] = a2.x; b[9] = a2.y; b[10] = a2.z; b[11] = a2.w;
        b[12] = a3.x; b[13] = a3.y; b[14] = a3.z; b[15] = a3.w;
    }
    const float* wp2 = &Ws2[k * KSTR + jb];
    float4 acc2 = b2[lane];
#pragma unroll
    for (int i = 0; i < 16; i++) {
        float4 wv = *(const float4*)&wp2[i * 16];
        acc2.x = fmaf(b[i], wv.x, acc2.x);
        acc2.y = fmaf(b[i], wv.y, acc2.y);
        acc2.z = fmaf(b[i], wv.z, acc2.z);
        acc2.w = fmaf(b[i], wv.w, acc2.w);
    }
    C[(size_t)n * 32 + lane] = acc2;
}

// ---------------- BN stats (standalone, for k_aggbd output) ----------------
__global__ __launch_bounds__(256) void k_stats(const float* __restrict__ X,
                                               float* __restrict__ st, int nrows) {
    int c = threadIdx.x & 127;
    int half = threadIdx.x >> 7;
    int rpb = (nrows + gridDim.x - 1) / gridDim.x;
    int r0 = blockIdx.x * rpb;
    int r1 = min(r0 + rpb, nrows);
    float s = 0.f, sq = 0.f;
    for (int r = r0 + half; r < r1; r += 2) {
        float v = X[(size_t)r * FF + c];
        s += v;
        sq += v * v;
    }
    atomicAdd(&st[c], s);
    atomicAdd(&st[FF + c], sq);
}

// ---------------- pooling with fused final BN ----------------
__global__ __launch_bounds__(128) void k_pool(const float* __restrict__ X,
                                              const int* __restrict__ batch,
                                              const float* __restrict__ st,
                                              const float* __restrict__ g,
                                              const float* __restrict__ be,
                                              float* __restrict__ out) {
    int c = threadIdx.x;
    const float inv_n = 1.0f / (float)NN;
    float mu = st[c] * inv_n;
    float var = st[FF + c] * inv_n - mu * mu;
    float a = g[c] * rsqrtf(var + BN_EPS);
    float b = be[c] - mu * a;
    int chunk = (NN + gridDim.x - 1) / gridDim.x;
    int r0 = blockIdx.x * chunk;
    int r1 = min(r0 + chunk, NN);
    if (r0 >= r1) return;
    float acc = 0.f;
    int cnt = 0;
    int cur = batch[r0];
    for (int r = r0; r < r1; r++) {
        int bb = batch[r];
        if (bb != cur) {
            atomicAdd(&out[(size_t)cur * FF + c], fmaf(a, acc, b * (float)cnt));
            acc = 0.f;
            cnt = 0;
            cur = bb;
        }
        acc += X[(size_t)r * FF + c];
        cnt++;
    }
    atomicAdd(&out[(size_t)cur * FF + c], fmaf(a, acc, b * (float)cnt));
}

extern "C" void kernel_launch(void* const* d_in, const int* in_sizes, int n_in,
                              void* d_out, int out_size, void* d_ws, size_t ws_size,
                              hipStream_t stream) {
    const float* x = (const float*)d_in[0];
    const int* ei = (const int*)d_in[1];
    const int* src = ei;
    const int* dst = ei + NE;
    const int* batch = (const int*)d_in[2];
    const float* gc_W1 = (const float*)d_in[4];
    const float* gc_b1 = (const float*)d_in[5];
    const float* gc_W2 = (const float*)d_in[6];
    const float* gc_b2 = (const float*)d_in[7];
    const float* gc_g = (const float*)d_in[8];
    const float* gc_be = (const float*)d_in[9];
    const float* h0_W1 = (const float*)d_in[10];
    const float* h0_b1 = (const float*)d_in[11];
    const float* h0_W2 = (const float*)d_in[12];
    const float* h0_b2 = (const float*)d_in[13];
    const float* h0_g = (const float*)d_in[14];
    const float* h0_be = (const float*)d_in[15];
    const float* h1_W1 = (const float*)d_in[16];
    const float* h1_b1 = (const float*)d_in[17];
    const float* h1_W2 = (const float*)d_in[18];
    const float* h1_b2 = (const float*)d_in[19];
    const float* h1_g = (const float*)d_in[20];
    const float* h1_be = (const float*)d_in[21];

    const size_t NF = (size_t)NN * FF;
    float* P0 = (float*)d_ws;
    float* P1 = P0 + NF;
    float* P2 = P1 + NF;
    float* stats = P2 + NF;
    int* deg = (int*)(stats + 5 * 256);
    int* cnt = deg + NN;
    int* offs = cnt + NN;
    int* bsum = offs + (NN + 4);
    int* boffs = bsum + 256;
    int* csr = boffs + 256;
    unsigned short* wbf = (unsigned short*)(csr + NE);  // 8 slots x 32768 shorts

    hipMemsetAsync(deg, 0, (size_t)2 * NN * sizeof(int), stream);
    hipMemsetAsync(stats, 0, 5 * 256 * sizeof(float), stream);
    hipMemsetAsync(d_out, 0, (size_t)GG * KF * DD * sizeof(float), stream);

    k_deg<<<(NE + 255) / 256, 256, 0, stream>>>(dst, deg);
    k_bsum<<<NB, 256, 0, stream>>>(deg, bsum);
    k_bscan<<<1, 256, 0, stream>>>(bsum, boffs);
    k_offs<<<NB, 256, 0, stream>>>(deg, boffs, offs);
    k_fill<<<(NE + 255) / 256, 256, 0, stream>>>(src, dst, offs, cnt, csr);
    k_wprep<<<(3 * 2 * 16384 + 255) / 256, 256, 0, stream>>>(gc_W1, gc_W2, wbf);
    k_wprep_h0<<<(2 * 16384 + 255) / 256, 256, 0, stream>>>(h0_W1, h0_W2, wbf);

    const int aggx_grid = ((NN + 63) / 64) * 8;  // 6256: tile x col-group (XCD)
    const int agg_grid = NN / 8;                 // 6250
    const int gemm_grid = (NN + 63) / 64;        // 782

    // ---- GC layers: XCD-sliced agg + MFMA bf16x3 gemm pair (stats fused) ----
    k_aggx<false, false><<<aggx_grid, 256, 0, stream>>>(
        (const float4*)x, offs, csr, nullptr, nullptr, nullptr, (float4*)P0);
    gemm_mfma<<<gemm_grid, 256, 0, stream>>>(
        (const float4*)P0, wbf + 0 * 32768, wbf + 1 * 32768, gc_b1, gc_b2, P2, stats);

    k_aggx<true, true><<<aggx_grid, 256, 0, stream>>>(
        (const float4*)P2, offs, csr, stats, gc_g, gc_be, (float4*)P0);
    gemm_mfma<<<gemm_grid, 256, 0, stream>>>(
        (const float4*)P0, wbf + 2 * 32768, wbf + 3 * 32768, gc_b1 + FF, gc_b2 + FF, P2, stats + 256);

    k_aggx<true, true><<<aggx_grid, 256, 0, stream>>>(
        (const float4*)P2, offs, csr, stats + 256, gc_g + FF, gc_be + FF, (float4*)P0);
    gemm_mfma<<<gemm_grid, 256, 0, stream>>>(
        (const float4*)P0, wbf + 4 * 32768, wbf + 5 * 32768, gc_b1 + 2 * FF, gc_b2 + 2 * FF, P2, stats + 512);

    // ---- head layer 0: XCD-sliced agg (GC2 BN, no relu) + MFMA (Wcat + blockdiag) --
    k_aggx<true, false><<<aggx_grid, 256, 0, stream>>>(
        (const float4*)P2, offs, csr, stats + 512, gc_g + 2 * FF, gc_be + 2 * FF, (float4*)P0);
    gemm_mfma<<<gemm_grid, 256, 0, stream>>>(
        (const float4*)P0, wbf + 6 * 32768, wbf + 7 * 32768, h0_b1, h0_b2, P1, stats + 768);

    // ---- head layer 1: fused agg(BN+relu) + double block-diag MLP ----
    k_aggbd<<<agg_grid, 256, 0, stream>>>(
        (const float4*)P1, offs, csr, stats + 768, h0_g, h0_be,
        h1_W1, (const float4*)h1_b1, h1_W2, (const float4*)h1_b2, (float4*)P2);
    k_stats<<<256, 256, 0, stream>>>(P2, stats + 1024, NN);

    // ---- pool with fused final BN ----
    k_pool<<<512, 128, 0, stream>>>(P2, batch, stats + 1024, h1_g, h1_be, (float*)d_out);
}

// Round 13
// 746.822 us; speedup vs baseline: 1.0987x; 1.0987x over previous
//
#include <hip/hip_runtime.h>

#define NN 50000
#define NE 800000
#define FF 128
#define KF 8
#define DD 16
#define GG 512
#define BN_EPS 1e-5f
#define NB 196   // ceil(NN/256)
#define KSTR 264 // padded k-block stride for block-diag weights

using s8v = __attribute__((ext_vector_type(8))) short;
using f4v = __attribute__((ext_vector_type(4))) float;

// ---------------- CSR build ----------------
__global__ void k_deg(const int* __restrict__ dst, int* __restrict__ deg) {
    int e = blockIdx.x * 256 + threadIdx.x;
    if (e < NE) atomicAdd(&deg[dst[e]], 1);
}

__global__ __launch_bounds__(256) void k_bsum(const int* __restrict__ deg, int* __restrict__ bsum) {
    int idx = blockIdx.x * 256 + threadIdx.x;
    int v = (idx < NN) ? deg[idx] : 0;
#pragma unroll
    for (int off = 32; off; off >>= 1) v += __shfl_down(v, off, 64);
    __shared__ int ws[4];
    if ((threadIdx.x & 63) == 0) ws[threadIdx.x >> 6] = v;
    __syncthreads();
    if (threadIdx.x == 0) bsum[blockIdx.x] = ws[0] + ws[1] + ws[2] + ws[3];
}

__global__ __launch_bounds__(256) void k_bscan(const int* __restrict__ bsum, int* __restrict__ boffs) {
    __shared__ int s[256];
    int tid = threadIdx.x;
    int v = (tid < NB) ? bsum[tid] : 0;
    s[tid] = v;
    __syncthreads();
    for (int off = 1; off < 256; off <<= 1) {
        int t = (tid >= off) ? s[tid - off] : 0;
        __syncthreads();
        s[tid] += t;
        __syncthreads();
    }
    if (tid < NB) boffs[tid] = s[tid] - v;  // exclusive
}

__global__ __launch_bounds__(256) void k_offs(const int* __restrict__ deg,
                                              const int* __restrict__ boffs,
                                              int* __restrict__ offs) {
    __shared__ int s[256];
    int tid = threadIdx.x;
    int idx = blockIdx.x * 256 + tid;
    int v = (idx < NN) ? deg[idx] : 0;
    s[tid] = v;
    __syncthreads();
    for (int off = 1; off < 256; off <<= 1) {
        int t = (tid >= off) ? s[tid - off] : 0;
        __syncthreads();
        s[tid] += t;
        __syncthreads();
    }
    int incl = s[tid];
    if (idx < NN) offs[idx] = boffs[blockIdx.x] + incl - v;
    if (idx == NN - 1) offs[NN] = boffs[blockIdx.x] + incl;
}

__global__ void k_fill(const int* __restrict__ src, const int* __restrict__ dst,
                       const int* __restrict__ offs, int* __restrict__ cnt,
                       int* __restrict__ csr) {
    int e = blockIdx.x * 256 + threadIdx.x;
    if (e < NE) {
        int d = dst[e];
        int p = atomicAdd(&cnt[d], 1);
        csr[offs[d] + p] = src[e];
    }
}

// ---------------- helpers ----------------
__device__ __forceinline__ void bn_coefs(const float* st, const float* g, const float* be,
                                         int lane, float4& a4, float4& b4) {
    const float inv_n = 1.0f / (float)NN;
    float av[4], bv[4];
#pragma unroll
    for (int t = 0; t < 4; t++) {
        int c = lane * 4 + t;
        float mu = st[c] * inv_n;
        float var = st[FF + c] * inv_n - mu * mu;
        float a = g[c] * rsqrtf(var + BN_EPS);
        av[t] = a;
        bv[t] = be[c] - mu * a;
    }
    a4 = make_float4(av[0], av[1], av[2], av[3]);
    b4 = make_float4(bv[0], bv[1], bv[2], bv[3]);
}

// split fp32 -> bf16 hi + bf16 lo (round-to-nearest-even both)
__device__ __forceinline__ void f2bf2(float v, unsigned short& hi, unsigned short& lo) {
    unsigned u = __float_as_uint(v);
    unsigned r = u + 0x7fffu + ((u >> 16) & 1u);
    hi = (unsigned short)(r >> 16);
    float hf = __uint_as_float(((unsigned)hi) << 16);
    float lf = v - hf;
    unsigned u2 = __float_as_uint(lf);
    unsigned r2 = u2 + 0x7fffu + ((u2 >> 16) & 1u);
    lo = (unsigned short)(r2 >> 16);
}

// ---------------- weight prep: fp32 [l][k][n] -> bf16 hi/lo transposed [n][k] -------
__global__ __launch_bounds__(256) void k_wprep(const float* __restrict__ W1,
                                               const float* __restrict__ W2,
                                               unsigned short* __restrict__ out) {
    int idx = blockIdx.x * 256 + threadIdx.x;  // over 3*2*16384
    if (idx >= 3 * 2 * 16384) return;
    int l = idx / (2 * 16384);
    int rem = idx % (2 * 16384);
    int mat = rem >> 14;
    int e = rem & 16383;
    int n = e >> 7, k = e & 127;
    const float* W = (mat == 0) ? (W1 + (size_t)l * 16384) : (W2 + (size_t)l * 16384);
    float v = W[k * 128 + n];
    unsigned short hi, lo;
    f2bf2(v, hi, lo);
    unsigned short* o = out + (size_t)((l * 2 + mat) * 2) * 16384;
    o[n * 128 + k] = hi;
    o[16384 + n * 128 + k] = lo;
}

// ---------------- weight prep for h0: Wcat^T (slot 6) + blockdiag(W2)^T (slot 7) ---
__global__ __launch_bounds__(256) void k_wprep_h0(const float* __restrict__ W1,  // [K,F,d]
                                                  const float* __restrict__ W2,  // [K,d,d]
                                                  unsigned short* __restrict__ out) {
    int idx = blockIdx.x * 256 + threadIdx.x;  // over 2*16384
    if (idx >= 2 * 16384) return;
    int mat = idx >> 14;
    int e = idx & 16383;
    int n = e >> 7, k = e & 127;  // n = output col, k = input feature
    float v;
    if (mat == 0) {
        // Wcat[k][n] = W1[n/16][k][n%16]
        v = W1[(n >> 4) * (FF * DD) + k * DD + (n & 15)];
    } else {
        // W2full[k][n] = (k/16==n/16) ? W2[n/16][k%16][n%16] : 0
        v = ((k >> 4) == (n >> 4)) ? W2[(n >> 4) * 256 + (k & 15) * DD + (n & 15)] : 0.f;
    }
    unsigned short hi, lo;
    f2bf2(v, hi, lo);
    unsigned short* o = out + (size_t)(6 + mat) * 32768;
    o[n * 128 + k] = hi;
    o[16384 + n * 128 + k] = lo;
}

// ---------------- aggregation with fused (optional) BN affine (+relu) on load ------
// R3/R11-proven config: 8 nodes/block, unroll 8, occ ~65% — at the gather plateau
// (~3.6 TB/s L2-miss BW; FETCH = per-XCD compulsory floor). XCD slicing (R12)
// and deeper ILP (R4) both falsified.
template <bool BN, bool RELU>
__global__ __launch_bounds__(256) void k_agg(const float4* __restrict__ X,
                                             const int* __restrict__ offs,
                                             const int* __restrict__ csr,
                                             const float* __restrict__ st,
                                             const float* __restrict__ g,
                                             const float* __restrict__ be,
                                             float4* __restrict__ Z) {
    int grp = threadIdx.x >> 5;
    int lane = threadIdx.x & 31;
    int n = blockIdx.x * 8 + grp;

    float4 a4 = make_float4(1.f, 1.f, 1.f, 1.f);
    float4 b4 = make_float4(0.f, 0.f, 0.f, 0.f);
    if (BN) bn_coefs(st, g, be, lane, a4, b4);

    auto apply = [&](float4 v) -> float4 {
        if (BN) {
            v.x = fmaf(v.x, a4.x, b4.x);
            v.y = fmaf(v.y, a4.y, b4.y);
            v.z = fmaf(v.z, a4.z, b4.z);
            v.w = fmaf(v.w, a4.w, b4.w);
        }
        if (RELU) {
            v.x = fmaxf(v.x, 0.f);
            v.y = fmaxf(v.y, 0.f);
            v.z = fmaxf(v.z, 0.f);
            v.w = fmaxf(v.w, 0.f);
        }
        return v;
    };
    auto add4 = [](float4& a, float4 b) {
        a.x += b.x; a.y += b.y; a.z += b.z; a.w += b.w;
    };

    float4 acc = apply(X[(size_t)n * 32 + lane]);
    int e0 = offs[n], e1 = offs[n + 1];
    int e = e0;
    for (; e + 8 <= e1; e += 8) {
        int s0 = csr[e], s1 = csr[e + 1], s2 = csr[e + 2], s3 = csr[e + 3];
        int s4 = csr[e + 4], s5 = csr[e + 5], s6 = csr[e + 6], s7 = csr[e + 7];
        float4 v0 = X[(size_t)s0 * 32 + lane];
        float4 v1 = X[(size_t)s1 * 32 + lane];
        float4 v2 = X[(size_t)s2 * 32 + lane];
        float4 v3 = X[(size_t)s3 * 32 + lane];
        float4 v4 = X[(size_t)s4 * 32 + lane];
        float4 v5 = X[(size_t)s5 * 32 + lane];
        float4 v6 = X[(size_t)s6 * 32 + lane];
        float4 v7 = X[(size_t)s7 * 32 + lane];
        v0 = apply(v0); v1 = apply(v1); v2 = apply(v2); v3 = apply(v3);
        v4 = apply(v4); v5 = apply(v5); v6 = apply(v6); v7 = apply(v7);
        add4(v0, v1); add4(v2, v3); add4(v4, v5); add4(v6, v7);
        add4(v0, v2); add4(v4, v6); add4(v0, v4); add4(acc, v0);
    }
    for (; e + 4 <= e1; e += 4) {
        int s0 = csr[e], s1 = csr[e + 1], s2 = csr[e + 2], s3 = csr[e + 3];
        float4 v0 = apply(X[(size_t)s0 * 32 + lane]);
        float4 v1 = apply(X[(size_t)s1 * 32 + lane]);
        float4 v2 = apply(X[(size_t)s2 * 32 + lane]);
        float4 v3 = apply(X[(size_t)s3 * 32 + lane]);
        add4(v0, v1); add4(v2, v3); add4(v0, v2); add4(acc, v0);
    }
    for (; e < e1; e++) {
        float4 v = apply(X[(size_t)csr[e] * 32 + lane]);
        add4(acc, v);
    }
    Z[(size_t)n * 32 + lane] = acc;
}

// ============ MFMA bf16x3 GEMM pair: C = relu(A@W1+b1)@W2 + b2, + stats ============
__global__ __launch_bounds__(256) void gemm_mfma(const float4* __restrict__ A,
                                                 const unsigned short* __restrict__ W1T,
                                                 const unsigned short* __restrict__ W2T,
                                                 const float* __restrict__ b1,
                                                 const float* __restrict__ b2,
                                                 float* __restrict__ C,
                                                 float* __restrict__ stout) {
    __shared__ __align__(16) unsigned short Abf[2 * 64 * 136];  // 34816 B
    __shared__ __align__(16) unsigned short Wch[2 * 128 * 40];  // 20480 B
    int tid = threadIdx.x;
    int row0 = blockIdx.x * 64;
    int w = tid >> 6, lane = tid & 63, quad = lane >> 4, lid = lane & 15;

    // stage A -> bf16 hi/lo (row-major)
#pragma unroll
    for (int i = 0; i < 8; i++) {
        int l = tid + i * 256;
        int r = l >> 5, q4 = l & 31;
        int gr = row0 + r;
        if (gr >= NN) gr = NN - 1;
        float4 v = A[(size_t)gr * 32 + q4];
        unsigned short h0, l0, h1, l1, h2, l2, h3, l3;
        f2bf2(v.x, h0, l0); f2bf2(v.y, h1, l1);
        f2bf2(v.z, h2, l2); f2bf2(v.w, h3, l3);
        *(ushort4*)&Abf[r * 136 + q4 * 4] = make_ushort4(h0, h1, h2, h3);
        *(ushort4*)&Abf[8704 + r * 136 + q4 * 4] = make_ushort4(l0, l1, l2, l3);
    }
    __syncthreads();

    f4v acc[8];
#pragma unroll
    for (int i = 0; i < 8; i++) acc[i] = 0;

    // ---- phase 1: z = relu(A@W1 + b1) ----
    for (int kc = 0; kc < 4; kc++) {
#pragma unroll
        for (int i = 0; i < 8; i++) {
            int l = tid + i * 256;
            int part = l >> 10, rem = l & 1023;
            int n = rem >> 3, kq = rem & 7;
            ushort4 v = *(const ushort4*)&W1T[(size_t)part * 16384 + n * 128 + kc * 32 + kq * 4];
            *(ushort4*)&Wch[part * 5120 + n * 40 + kq * 4] = v;
        }
        __syncthreads();
        s8v ah = *(const s8v*)&Abf[(w * 16 + lid) * 136 + kc * 32 + quad * 8];
        s8v al = *(const s8v*)&Abf[8704 + (w * 16 + lid) * 136 + kc * 32 + quad * 8];
#pragma unroll
        for (int n0 = 0; n0 < 8; n0++) {
            s8v bh = *(const s8v*)&Wch[(n0 * 16 + lid) * 40 + quad * 8];
            s8v bl = *(const s8v*)&Wch[5120 + (n0 * 16 + lid) * 40 + quad * 8];
            acc[n0] = __builtin_amdgcn_mfma_f32_16x16x32_bf16(ah, bh, acc[n0], 0, 0, 0);
            acc[n0] = __builtin_amdgcn_mfma_f32_16x16x32_bf16(al, bh, acc[n0], 0, 0, 0);
            acc[n0] = __builtin_amdgcn_mfma_f32_16x16x32_bf16(ah, bl, acc[n0], 0, 0, 0);
        }
        __syncthreads();
    }

    // z = relu(acc+b1) -> Abf bf16 hi/lo (this wave's rows)
#pragma unroll
    for (int n0 = 0; n0 < 8; n0++) {
        int c = n0 * 16 + lid;
        float bb = b1[c];
#pragma unroll
        for (int rr = 0; rr < 4; rr++) {
            int lr = w * 16 + quad * 4 + rr;
            float z = fmaxf(acc[n0][rr] + bb, 0.f);
            unsigned short h, lo2;
            f2bf2(z, h, lo2);
            Abf[lr * 136 + c] = h;
            Abf[8704 + lr * 136 + c] = lo2;
        }
        acc[n0] = 0;
    }

    // ---- phase 2: C = z@W2 + b2 ----
    for (int kc = 0; kc < 4; kc++) {
#pragma unroll
        for (int i = 0; i < 8; i++) {
            int l = tid + i * 256;
            int part = l >> 10, rem = l & 1023;
            int n = rem >> 3, kq = rem & 7;
            ushort4 v = *(const ushort4*)&W2T[(size_t)part * 16384 + n * 128 + kc * 32 + kq * 4];
            *(ushort4*)&Wch[part * 5120 + n * 40 + kq * 4] = v;
        }
        __syncthreads();
        s8v ah = *(const s8v*)&Abf[(w * 16 + lid) * 136 + kc * 32 + quad * 8];
        s8v al = *(const s8v*)&Abf[8704 + (w * 16 + lid) * 136 + kc * 32 + quad * 8];
#pragma unroll
        for (int n0 = 0; n0 < 8; n0++) {
            s8v bh = *(const s8v*)&Wch[(n0 * 16 + lid) * 40 + quad * 8];
            s8v bl = *(const s8v*)&Wch[5120 + (n0 * 16 + lid) * 40 + quad * 8];
            acc[n0] = __builtin_amdgcn_mfma_f32_16x16x32_bf16(ah, bh, acc[n0], 0, 0, 0);
            acc[n0] = __builtin_amdgcn_mfma_f32_16x16x32_bf16(al, bh, acc[n0], 0, 0, 0);
            acc[n0] = __builtin_amdgcn_mfma_f32_16x16x32_bf16(ah, bl, acc[n0], 0, 0, 0);
        }
        __syncthreads();
    }

    // ---- epilogue: bias, store, stats ----
    float* Sred = (float*)Wch;
#pragma unroll
    for (int n0 = 0; n0 < 8; n0++) {
        int c = n0 * 16 + lid;
        float bb = b2[c];
        float s = 0.f, q = 0.f;
#pragma unroll
        for (int rr = 0; rr < 4; rr++) {
            int grow = row0 + w * 16 + quad * 4 + rr;
            if (grow < NN) {
                float v = acc[n0][rr] + bb;
                C[(size_t)grow * 128 + c] = v;
                s += v;
                q += v * v;
            }
        }
        s += __shfl_xor(s, 16); s += __shfl_xor(s, 32);
        q += __shfl_xor(q, 16); q += __shfl_xor(q, 32);
        if (quad == 0) {
            Sred[w * 128 + c] = s;
            Sred[512 + w * 128 + c] = q;
        }
    }
    __syncthreads();
    if (tid < 128) {
        float s = Sred[tid] + Sred[128 + tid] + Sred[256 + tid] + Sred[384 + tid];
        float q = Sred[512 + tid] + Sred[640 + tid] + Sred[768 + tid] + Sred[896 + tid];
        atomicAdd(&stout[tid], s);
        atomicAdd(&stout[FF + tid], q);
    }
}

// ---------------- fused h1: agg(BN+relu on load) + double block-diag MLP -----------
__global__ __launch_bounds__(256) void k_aggbd(const float4* __restrict__ X,
                                               const int* __restrict__ offs,
                                               const int* __restrict__ csr,
                                               const float* __restrict__ st,
                                               const float* __restrict__ g,
                                               const float* __restrict__ be,
                                               const float* __restrict__ W1,
                                               const float4* __restrict__ b1,
                                               const float* __restrict__ W2,
                                               const float4* __restrict__ b2,
                                               float4* __restrict__ C) {
    __shared__ float As[8][128];
    __shared__ float Ts[8][128];
    __shared__ float Ws1[KF * KSTR];
    __shared__ float Ws2[KF * KSTR];
    int grp = threadIdx.x >> 5, lane = threadIdx.x & 31;
    int n = blockIdx.x * 8 + grp;

    for (int l = threadIdx.x; l < KF * 256; l += 256) {
        int k = l >> 8, r = l & 255;
        Ws1[k * KSTR + r] = W1[l];
        Ws2[k * KSTR + r] = W2[l];
    }

    float4 a4, b4;
    bn_coefs(st, g, be, lane, a4, b4);
    auto apply = [&](float4 v) -> float4 {
        v.x = fmaxf(fmaf(v.x, a4.x, b4.x), 0.f);
        v.y = fmaxf(fmaf(v.y, a4.y, b4.y), 0.f);
        v.z = fmaxf(fmaf(v.z, a4.z, b4.z), 0.f);
        v.w = fmaxf(fmaf(v.w, a4.w, b4.w), 0.f);
        return v;
    };
    auto add4 = [](float4& a, float4 b) {
        a.x += b.x; a.y += b.y; a.z += b.z; a.w += b.w;
    };

    float4 acc = apply(X[(size_t)n * 32 + lane]);
    int e0 = offs[n], e1 = offs[n + 1];
    int e = e0;
    for (; e + 8 <= e1; e += 8) {
        int s0 = csr[e], s1 = csr[e + 1], s2 = csr[e + 2], s3 = csr[e + 3];
        int s4 = csr[e + 4], s5 = csr[e + 5], s6 = csr[e + 6], s7 = csr[e + 7];
        float4 v0 = X[(size_t)s0 * 32 + lane];
        float4 v1 = X[(size_t)s1 * 32 + lane];
        float4 v2 = X[(size_t)s2 * 32 + lane];
        float4 v3 = X[(size_t)s3 * 32 + lane];
        float4 v4 = X[(size_t)s4 * 32 + lane];
        float4 v5 = X[(size_t)s5 * 32 + lane];
        float4 v6 = X[(size_t)s6 * 32 + lane];
        float4 v7 = X[(size_t)s7 * 32 + lane];
        v0 = apply(v0); v1 = apply(v1); v2 = apply(v2); v3 = apply(v3);
        v4 = apply(v4); v5 = apply(v5); v6 = apply(v6); v7 = apply(v7);
        add4(v0, v1); add4(v2, v3); add4(v4, v5); add4(v6, v7);
        add4(v0, v2); add4(v4, v6); add4(v0, v4); add4(acc, v0);
    }
    for (; e + 4 <= e1; e += 4) {
        int s0 = csr[e], s1 = csr[e + 1], s2 = csr[e + 2], s3 = csr[e + 3];
        float4 v0 = apply(X[(size_t)s0 * 32 + lane]);
        float4 v1 = apply(X[(size_t)s1 * 32 + lane]);
        float4 v2 = apply(X[(size_t)s2 * 32 + lane]);
        float4 v3 = apply(X[(size_t)s3 * 32 + lane]);
        add4(v0, v1); add4(v2, v3); add4(v0, v2); add4(acc, v0);
    }
    for (; e < e1; e++) {
        float4 v = apply(X[(size_t)csr[e] * 32 + lane]);
        add4(acc, v);
    }
    ((float4*)&As[grp][0])[lane] = acc;
    __syncthreads();

    int k = lane >> 2, jb = (lane & 3) * 4;
    float a[16];
    {
        const float4* As4 = (const float4*)&As[grp][k * 16];
        float4 a0 = As4[0], a1 = As4[1], a2 = As4[2], a3 = As4[3];
        a[0] = a0.x; a[1] = a0.y; a[2] = a0.z; a[3] = a0.w;
        a[4] = a1.x; a[5] = a1.y; a[6] = a1.z; a[7] = a1.w;
        a[8] = a2.x; a[9] = a2.y; a[10] = a2.z; a[11] = a2.w;
        a[12] = a3.x; a[13] = a3.y; a[14] = a3.z; a[15] = a3.w;
    }
    const float* wp1 = &Ws1[k * KSTR + jb];
    float4 t = b1[lane];
#pragma unroll
    for (int i = 0; i < 16; i++) {
        float4 wv = *(const float4*)&wp1[i * 16];
        t.x = fmaf(a[i], wv.x, t.x);
        t.y = fmaf(a[i], wv.y, t.y);
        t.z = fmaf(a[i], wv.z, t.z);
        t.w = fmaf(a[i], wv.w, t.w);
    }
    t.x = fmaxf(t.x, 0.f); t.y = fmaxf(t.y, 0.f);
    t.z = fmaxf(t.z, 0.f); t.w = fmaxf(t.w, 0.f);
    ((float4*)&Ts[grp][0])[lane] = t;
    __syncthreads();

    float b[16];
    {
        const float4* Ts4 = (const float4*)&Ts[grp][k * 16];
        float4 a0 = Ts4[0], a1 = Ts4[1], a2 = Ts4[2], a3 = Ts4[3];
        b[0] = a0.x; b[1] = a0.y; b[2] = a0.z; b[3] = a0.w;
        b[4] = a1.x; b[5] = a1.y; b[6] = a1.z; b[7] = a1.w;
        b[8] = a2.x; b[9] = a2.y; b[10] = a2.z; b[11] = a2.w;
        b[12] = a3.x; b[13] = a3.y; b[14] = a3.z; b[15] = a3.w;
    }
    const float* wp2 = &Ws2[k * KSTR + jb];
    float4 acc2 = b2[lane];
#pragma unroll
    for (int i = 0; i < 16; i++) {
        float4 wv = *(const float4*)&wp2[i * 16];
        acc2.x = fmaf(b[i], wv.x, acc2.x);
        acc2.y = fmaf(b[i], wv.y, acc2.y);
        acc2.z = fmaf(b[i], wv.z, acc2.z);
        acc2.w = fmaf(b[i], wv.w, acc2.w);
    }
    C[(size_t)n * 32 + lane] = acc2;
}

// ---------------- BN stats (standalone, for k_aggbd output) ----------------
__global__ __launch_bounds__(256) void k_stats(const float* __restrict__ X,
                                               float* __restrict__ st, int nrows) {
    int c = threadIdx.x & 127;
    int half = threadIdx.x >> 7;
    int rpb = (nrows + gridDim.x - 1) / gridDim.x;
    int r0 = blockIdx.x * rpb;
    int r1 = min(r0 + rpb, nrows);
    float s = 0.f, sq = 0.f;
    for (int r = r0 + half; r < r1; r += 2) {
        float v = X[(size_t)r * FF + c];
        s += v;
        sq += v * v;
    }
    atomicAdd(&st[c], s);
    atomicAdd(&st[FF + c], sq);
}

// ---------------- pooling with fused final BN ----------------
__global__ __launch_bounds__(128) void k_pool(const float* __restrict__ X,
                                              const int* __restrict__ batch,
                                              const float* __restrict__ st,
                                              const float* __restrict__ g,
                                              const float* __restrict__ be,
                                              float* __restrict__ out) {
    int c = threadIdx.x;
    const float inv_n = 1.0f / (float)NN;
    float mu = st[c] * inv_n;
    float var = st[FF + c] * inv_n - mu * mu;
    float a = g[c] * rsqrtf(var + BN_EPS);
    float b = be[c] - mu * a;
    int chunk = (NN + gridDim.x - 1) / gridDim.x;
    int r0 = blockIdx.x * chunk;
    int r1 = min(r0 + chunk, NN);
    if (r0 >= r1) return;
    float acc = 0.f;
    int cnt = 0;
    int cur = batch[r0];
    for (int r = r0; r < r1; r++) {
        int bb = batch[r];
        if (bb != cur) {
            atomicAdd(&out[(size_t)cur * FF + c], fmaf(a, acc, b * (float)cnt));
            acc = 0.f;
            cnt = 0;
            cur = bb;
        }
        acc += X[(size_t)r * FF + c];
        cnt++;
    }
    atomicAdd(&out[(size_t)cur * FF + c], fmaf(a, acc, b * (float)cnt));
}

extern "C" void kernel_launch(void* const* d_in, const int* in_sizes, int n_in,
                              void* d_out, int out_size, void* d_ws, size_t ws_size,
                              hipStream_t stream) {
    const float* x = (const float*)d_in[0];
    const int* ei = (const int*)d_in[1];
    const int* src = ei;
    const int* dst = ei + NE;
    const int* batch = (const int*)d_in[2];
    const float* gc_W1 = (const float*)d_in[4];
    const float* gc_b1 = (const float*)d_in[5];
    const float* gc_W2 = (const float*)d_in[6];
    const float* gc_b2 = (const float*)d_in[7];
    const float* gc_g = (const float*)d_in[8];
    const float* gc_be = (const float*)d_in[9];
    const float* h0_W1 = (const float*)d_in[10];
    const float* h0_b1 = (const float*)d_in[11];
    const float* h0_W2 = (const float*)d_in[12];
    const float* h0_b2 = (const float*)d_in[13];
    const float* h0_g = (const float*)d_in[14];
    const float* h0_be = (const float*)d_in[15];
    const float* h1_W1 = (const float*)d_in[16];
    const float* h1_b1 = (const float*)d_in[17];
    const float* h1_W2 = (const float*)d_in[18];
    const float* h1_b2 = (const float*)d_in[19];
    const float* h1_g = (const float*)d_in[20];
    const float* h1_be = (const float*)d_in[21];

    const size_t NF = (size_t)NN * FF;
    float* P0 = (float*)d_ws;
    float* P1 = P0 + NF;
    float* P2 = P1 + NF;
    float* stats = P2 + NF;
    int* deg = (int*)(stats + 5 * 256);
    int* cnt = deg + NN;
    int* offs = cnt + NN;
    int* bsum = offs + (NN + 4);
    int* boffs = bsum + 256;
    int* csr = boffs + 256;
    unsigned short* wbf = (unsigned short*)(csr + NE);  // 8 slots x 32768 shorts

    hipMemsetAsync(deg, 0, (size_t)2 * NN * sizeof(int), stream);
    hipMemsetAsync(stats, 0, 5 * 256 * sizeof(float), stream);
    hipMemsetAsync(d_out, 0, (size_t)GG * KF * DD * sizeof(float), stream);

    k_deg<<<(NE + 255) / 256, 256, 0, stream>>>(dst, deg);
    k_bsum<<<NB, 256, 0, stream>>>(deg, bsum);
    k_bscan<<<1, 256, 0, stream>>>(bsum, boffs);
    k_offs<<<NB, 256, 0, stream>>>(deg, boffs, offs);
    k_fill<<<(NE + 255) / 256, 256, 0, stream>>>(src, dst, offs, cnt, csr);
    k_wprep<<<(3 * 2 * 16384 + 255) / 256, 256, 0, stream>>>(gc_W1, gc_W2, wbf);
    k_wprep_h0<<<(2 * 16384 + 255) / 256, 256, 0, stream>>>(h0_W1, h0_W2, wbf);

    const int agg_grid = NN / 8;            // 6250
    const int gemm_grid = (NN + 63) / 64;   // 782

    // ---- GC layers: agg + MFMA bf16x3 gemm pair (stats fused) ----
    k_agg<false, false><<<agg_grid, 256, 0, stream>>>(
        (const float4*)x, offs, csr, nullptr, nullptr, nullptr, (float4*)P0);
    gemm_mfma<<<gemm_grid, 256, 0, stream>>>(
        (const float4*)P0, wbf + 0 * 32768, wbf + 1 * 32768, gc_b1, gc_b2, P2, stats);

    k_agg<true, true><<<agg_grid, 256, 0, stream>>>(
        (const float4*)P2, offs, csr, stats, gc_g, gc_be, (float4*)P0);
    gemm_mfma<<<gemm_grid, 256, 0, stream>>>(
        (const float4*)P0, wbf + 2 * 32768, wbf + 3 * 32768, gc_b1 + FF, gc_b2 + FF, P2, stats + 256);

    k_agg<true, true><<<agg_grid, 256, 0, stream>>>(
        (const float4*)P2, offs, csr, stats + 256, gc_g + FF, gc_be + FF, (float4*)P0);
    gemm_mfma<<<gemm_grid, 256, 0, stream>>>(
        (const float4*)P0, wbf + 4 * 32768, wbf + 5 * 32768, gc_b1 + 2 * FF, gc_b2 + 2 * FF, P2, stats + 512);

    // ---- head layer 0: agg (GC2 BN, no relu) + MFMA (Wcat + blockdiag) ----
    k_agg<true, false><<<agg_grid, 256, 0, stream>>>(
        (const float4*)P2, offs, csr, stats + 512, gc_g + 2 * FF, gc_be + 2 * FF, (float4*)P0);
    gemm_mfma<<<gemm_grid, 256, 0, stream>>>(
        (const float4*)P0, wbf + 6 * 32768, wbf + 7 * 32768, h0_b1, h0_b2, P1, stats + 768);

    // ---- head layer 1: fused agg(BN+relu) + double block-diag MLP ----
    k_aggbd<<<agg_grid, 256, 0, stream>>>(
        (const float4*)P1, offs, csr, stats + 768, h0_g, h0_be,
        h1_W1, (const float4*)h1_b1, h1_W2, (const float4*)h1_b2, (float4*)P2);
    k_stats<<<256, 256, 0, stream>>>(P2, stats + 1024, NN);

    // ---- pool with fused final BN ----
    k_pool<<<512, 128, 0, stream>>>(P2, batch, stats + 1024, h1_g, h1_be, (float*)d_out);
}

// Round 14
// 737.655 us; speedup vs baseline: 1.1124x; 1.0124x over previous
//
#include <hip/hip_runtime.h>

#define NN 50000
#define NE 800000
#define FF 128
#define KF 8
#define DD 16
#define GG 512
#define BN_EPS 1e-5f
#define NB 196   // ceil(NN/256)
#define KSTR 264 // padded k-block stride for block-diag weights (flat staging)
#define BSTR 20  // padded per-16-col block stride (floats) in aggbd As/Ts: banks k*20%32 all-distinct

using s8v = __attribute__((ext_vector_type(8))) short;
using f4v = __attribute__((ext_vector_type(4))) float;

// ---------------- CSR build ----------------
__global__ void k_deg(const int* __restrict__ dst, int* __restrict__ deg) {
    int e = blockIdx.x * 256 + threadIdx.x;
    if (e < NE) atomicAdd(&deg[dst[e]], 1);
}

__global__ __launch_bounds__(256) void k_bsum(const int* __restrict__ deg, int* __restrict__ bsum) {
    int idx = blockIdx.x * 256 + threadIdx.x;
    int v = (idx < NN) ? deg[idx] : 0;
#pragma unroll
    for (int off = 32; off; off >>= 1) v += __shfl_down(v, off, 64);
    __shared__ int ws[4];
    if ((threadIdx.x & 63) == 0) ws[threadIdx.x >> 6] = v;
    __syncthreads();
    if (threadIdx.x == 0) bsum[blockIdx.x] = ws[0] + ws[1] + ws[2] + ws[3];
}

__global__ __launch_bounds__(256) void k_bscan(const int* __restrict__ bsum, int* __restrict__ boffs) {
    __shared__ int s[256];
    int tid = threadIdx.x;
    int v = (tid < NB) ? bsum[tid] : 0;
    s[tid] = v;
    __syncthreads();
    for (int off = 1; off < 256; off <<= 1) {
        int t = (tid >= off) ? s[tid - off] : 0;
        __syncthreads();
        s[tid] += t;
        __syncthreads();
    }
    if (tid < NB) boffs[tid] = s[tid] - v;  // exclusive
}

__global__ __launch_bounds__(256) void k_offs(const int* __restrict__ deg,
                                              const int* __restrict__ boffs,
                                              int* __restrict__ offs) {
    __shared__ int s[256];
    int tid = threadIdx.x;
    int idx = blockIdx.x * 256 + tid;
    int v = (idx < NN) ? deg[idx] : 0;
    s[tid] = v;
    __syncthreads();
    for (int off = 1; off < 256; off <<= 1) {
        int t = (tid >= off) ? s[tid - off] : 0;
        __syncthreads();
        s[tid] += t;
        __syncthreads();
    }
    int incl = s[tid];
    if (idx < NN) offs[idx] = boffs[blockIdx.x] + incl - v;
    if (idx == NN - 1) offs[NN] = boffs[blockIdx.x] + incl;
}

__global__ void k_fill(const int* __restrict__ src, const int* __restrict__ dst,
                       const int* __restrict__ offs, int* __restrict__ cnt,
                       int* __restrict__ csr) {
    int e = blockIdx.x * 256 + threadIdx.x;
    if (e < NE) {
        int d = dst[e];
        int p = atomicAdd(&cnt[d], 1);
        csr[offs[d] + p] = src[e];
    }
}

// ---------------- helpers ----------------
__device__ __forceinline__ void bn_coefs(const float* st, const float* g, const float* be,
                                         int lane, float4& a4, float4& b4) {
    const float inv_n = 1.0f / (float)NN;
    float av[4], bv[4];
#pragma unroll
    for (int t = 0; t < 4; t++) {
        int c = lane * 4 + t;
        float mu = st[c] * inv_n;
        float var = st[FF + c] * inv_n - mu * mu;
        float a = g[c] * rsqrtf(var + BN_EPS);
        av[t] = a;
        bv[t] = be[c] - mu * a;
    }
    a4 = make_float4(av[0], av[1], av[2], av[3]);
    b4 = make_float4(bv[0], bv[1], bv[2], bv[3]);
}

// split fp32 -> bf16 hi + bf16 lo (round-to-nearest-even both)
__device__ __forceinline__ void f2bf2(float v, unsigned short& hi, unsigned short& lo) {
    unsigned u = __float_as_uint(v);
    unsigned r = u + 0x7fffu + ((u >> 16) & 1u);
    hi = (unsigned short)(r >> 16);
    float hf = __uint_as_float(((unsigned)hi) << 16);
    float lf = v - hf;
    unsigned u2 = __float_as_uint(lf);
    unsigned r2 = u2 + 0x7fffu + ((u2 >> 16) & 1u);
    lo = (unsigned short)(r2 >> 16);
}

// ---------------- weight prep: fp32 [l][k][n] -> bf16 hi/lo transposed [n][k] -------
__global__ __launch_bounds__(256) void k_wprep(const float* __restrict__ W1,
                                               const float* __restrict__ W2,
                                               unsigned short* __restrict__ out) {
    int idx = blockIdx.x * 256 + threadIdx.x;  // over 3*2*16384
    if (idx >= 3 * 2 * 16384) return;
    int l = idx / (2 * 16384);
    int rem = idx % (2 * 16384);
    int mat = rem >> 14;
    int e = rem & 16383;
    int n = e >> 7, k = e & 127;
    const float* W = (mat == 0) ? (W1 + (size_t)l * 16384) : (W2 + (size_t)l * 16384);
    float v = W[k * 128 + n];
    unsigned short hi, lo;
    f2bf2(v, hi, lo);
    unsigned short* o = out + (size_t)((l * 2 + mat) * 2) * 16384;
    o[n * 128 + k] = hi;
    o[16384 + n * 128 + k] = lo;
}

// ---------------- weight prep for h0: Wcat^T (slot 6) + blockdiag(W2)^T (slot 7) ---
__global__ __launch_bounds__(256) void k_wprep_h0(const float* __restrict__ W1,  // [K,F,d]
                                                  const float* __restrict__ W2,  // [K,d,d]
                                                  unsigned short* __restrict__ out) {
    int idx = blockIdx.x * 256 + threadIdx.x;  // over 2*16384
    if (idx >= 2 * 16384) return;
    int mat = idx >> 14;
    int e = idx & 16383;
    int n = e >> 7, k = e & 127;
    float v;
    if (mat == 0) {
        v = W1[(n >> 4) * (FF * DD) + k * DD + (n & 15)];
    } else {
        v = ((k >> 4) == (n >> 4)) ? W2[(n >> 4) * 256 + (k & 15) * DD + (n & 15)] : 0.f;
    }
    unsigned short hi, lo;
    f2bf2(v, hi, lo);
    unsigned short* o = out + (size_t)(6 + mat) * 32768;
    o[n * 128 + k] = hi;
    o[16384 + n * 128 + k] = lo;
}

// ---------------- aggregation, fused BN(+relu) on load, bf16 hi/lo plane output ----
// R3-proven gather (8 nodes/block, unroll 8). Output split moved here from gemm's
// staging (this kernel is latency-bound with VALU headroom; gemm was staging-bound).
template <bool BN, bool RELU>
__global__ __launch_bounds__(256) void k_agg(const float4* __restrict__ X,
                                             const int* __restrict__ offs,
                                             const int* __restrict__ csr,
                                             const float* __restrict__ st,
                                             const float* __restrict__ g,
                                             const float* __restrict__ be,
                                             unsigned short* __restrict__ Zhi,
                                             unsigned short* __restrict__ Zlo) {
    int grp = threadIdx.x >> 5;
    int lane = threadIdx.x & 31;
    int n = blockIdx.x * 8 + grp;

    float4 a4 = make_float4(1.f, 1.f, 1.f, 1.f);
    float4 b4 = make_float4(0.f, 0.f, 0.f, 0.f);
    if (BN) bn_coefs(st, g, be, lane, a4, b4);

    auto apply = [&](float4 v) -> float4 {
        if (BN) {
            v.x = fmaf(v.x, a4.x, b4.x);
            v.y = fmaf(v.y, a4.y, b4.y);
            v.z = fmaf(v.z, a4.z, b4.z);
            v.w = fmaf(v.w, a4.w, b4.w);
        }
        if (RELU) {
            v.x = fmaxf(v.x, 0.f);
            v.y = fmaxf(v.y, 0.f);
            v.z = fmaxf(v.z, 0.f);
            v.w = fmaxf(v.w, 0.f);
        }
        return v;
    };
    auto add4 = [](float4& a, float4 b) {
        a.x += b.x; a.y += b.y; a.z += b.z; a.w += b.w;
    };

    float4 acc = apply(X[(size_t)n * 32 + lane]);
    int e0 = offs[n], e1 = offs[n + 1];
    int e = e0;
    for (; e + 8 <= e1; e += 8) {
        int s0 = csr[e], s1 = csr[e + 1], s2 = csr[e + 2], s3 = csr[e + 3];
        int s4 = csr[e + 4], s5 = csr[e + 5], s6 = csr[e + 6], s7 = csr[e + 7];
        float4 v0 = X[(size_t)s0 * 32 + lane];
        float4 v1 = X[(size_t)s1 * 32 + lane];
        float4 v2 = X[(size_t)s2 * 32 + lane];
        float4 v3 = X[(size_t)s3 * 32 + lane];
        float4 v4 = X[(size_t)s4 * 32 + lane];
        float4 v5 = X[(size_t)s5 * 32 + lane];
        float4 v6 = X[(size_t)s6 * 32 + lane];
        float4 v7 = X[(size_t)s7 * 32 + lane];
        v0 = apply(v0); v1 = apply(v1); v2 = apply(v2); v3 = apply(v3);
        v4 = apply(v4); v5 = apply(v5); v6 = apply(v6); v7 = apply(v7);
        add4(v0, v1); add4(v2, v3); add4(v4, v5); add4(v6, v7);
        add4(v0, v2); add4(v4, v6); add4(v0, v4); add4(acc, v0);
    }
    for (; e + 4 <= e1; e += 4) {
        int s0 = csr[e], s1 = csr[e + 1], s2 = csr[e + 2], s3 = csr[e + 3];
        float4 v0 = apply(X[(size_t)s0 * 32 + lane]);
        float4 v1 = apply(X[(size_t)s1 * 32 + lane]);
        float4 v2 = apply(X[(size_t)s2 * 32 + lane]);
        float4 v3 = apply(X[(size_t)s3 * 32 + lane]);
        add4(v0, v1); add4(v2, v3); add4(v0, v2); add4(acc, v0);
    }
    for (; e < e1; e++) {
        float4 v = apply(X[(size_t)csr[e] * 32 + lane]);
        add4(acc, v);
    }
    unsigned short h0, l0, h1, l1, h2, l2, h3, l3;
    f2bf2(acc.x, h0, l0); f2bf2(acc.y, h1, l1);
    f2bf2(acc.z, h2, l2); f2bf2(acc.w, h3, l3);
    *(ushort4*)&Zhi[(size_t)n * 128 + lane * 4] = make_ushort4(h0, h1, h2, h3);
    *(ushort4*)&Zlo[(size_t)n * 128 + lane * 4] = make_ushort4(l0, l1, l2, l3);
}

// ============ MFMA bf16x3 GEMM pair: C = relu(A@W1+b1)@W2 + b2, + stats ============
// A arrives pre-split as bf16 hi/lo planes (k_agg epilogue) -> staging is pure copies.
__global__ __launch_bounds__(256) void gemm_mfma(const unsigned short* __restrict__ Zhi,
                                                 const unsigned short* __restrict__ Zlo,
                                                 const unsigned short* __restrict__ W1T,
                                                 const unsigned short* __restrict__ W2T,
                                                 const float* __restrict__ b1,
                                                 const float* __restrict__ b2,
                                                 float* __restrict__ C,
                                                 float* __restrict__ stout) {
    __shared__ __align__(16) unsigned short Abf[2 * 64 * 136];  // 34816 B
    __shared__ __align__(16) unsigned short Wch[2 * 128 * 40];  // 20480 B
    int tid = threadIdx.x;
    int row0 = blockIdx.x * 64;
    int w = tid >> 6, lane = tid & 63, quad = lane >> 4, lid = lane & 15;

    // stage A hi/lo planes -> LDS (pure 16B copies)
#pragma unroll
    for (int i = 0; i < 8; i++) {
        int l = tid + i * 256;           // 0..2047: plane x 64 rows x 16 groups-of-8
        int plane = l >> 10, rem = l & 1023;
        int r = rem >> 4, q = rem & 15;
        int gr = row0 + r;
        if (gr >= NN) gr = NN - 1;
        const unsigned short* src = (plane == 0) ? Zhi : Zlo;
        uint4 v = *(const uint4*)&src[(size_t)gr * 128 + q * 8];
        *(uint4*)&Abf[plane * 8704 + r * 136 + q * 8] = v;
    }
    __syncthreads();

    f4v acc[8];
#pragma unroll
    for (int i = 0; i < 8; i++) acc[i] = 0;

    // ---- phase 1: z = relu(A@W1 + b1) ----
    for (int kc = 0; kc < 4; kc++) {
#pragma unroll
        for (int i = 0; i < 8; i++) {
            int l = tid + i * 256;
            int part = l >> 10, rem = l & 1023;
            int n = rem >> 3, kq = rem & 7;
            ushort4 v = *(const ushort4*)&W1T[(size_t)part * 16384 + n * 128 + kc * 32 + kq * 4];
            *(ushort4*)&Wch[part * 5120 + n * 40 + kq * 4] = v;
        }
        __syncthreads();
        s8v ah = *(const s8v*)&Abf[(w * 16 + lid) * 136 + kc * 32 + quad * 8];
        s8v al = *(const s8v*)&Abf[8704 + (w * 16 + lid) * 136 + kc * 32 + quad * 8];
#pragma unroll
        for (int n0 = 0; n0 < 8; n0++) {
            s8v bh = *(const s8v*)&Wch[(n0 * 16 + lid) * 40 + quad * 8];
            s8v bl = *(const s8v*)&Wch[5120 + (n0 * 16 + lid) * 40 + quad * 8];
            acc[n0] = __builtin_amdgcn_mfma_f32_16x16x32_bf16(ah, bh, acc[n0], 0, 0, 0);
            acc[n0] = __builtin_amdgcn_mfma_f32_16x16x32_bf16(al, bh, acc[n0], 0, 0, 0);
            acc[n0] = __builtin_amdgcn_mfma_f32_16x16x32_bf16(ah, bl, acc[n0], 0, 0, 0);
        }
        __syncthreads();
    }

    // z = relu(acc+b1) -> Abf bf16 hi/lo (this wave's rows)
#pragma unroll
    for (int n0 = 0; n0 < 8; n0++) {
        int c = n0 * 16 + lid;
        float bb = b1[c];
#pragma unroll
        for (int rr = 0; rr < 4; rr++) {
            int lr = w * 16 + quad * 4 + rr;
            float z = fmaxf(acc[n0][rr] + bb, 0.f);
            unsigned short h, lo2;
            f2bf2(z, h, lo2);
            Abf[lr * 136 + c] = h;
            Abf[8704 + lr * 136 + c] = lo2;
        }
        acc[n0] = 0;
    }

    // ---- phase 2: C = z@W2 + b2 ----
    for (int kc = 0; kc < 4; kc++) {
#pragma unroll
        for (int i = 0; i < 8; i++) {
            int l = tid + i * 256;
            int part = l >> 10, rem = l & 1023;
            int n = rem >> 3, kq = rem & 7;
            ushort4 v = *(const ushort4*)&W2T[(size_t)part * 16384 + n * 128 + kc * 32 + kq * 4];
            *(ushort4*)&Wch[part * 5120 + n * 40 + kq * 4] = v;
        }
        __syncthreads();
        s8v ah = *(const s8v*)&Abf[(w * 16 + lid) * 136 + kc * 32 + quad * 8];
        s8v al = *(const s8v*)&Abf[8704 + (w * 16 + lid) * 136 + kc * 32 + quad * 8];
#pragma unroll
        for (int n0 = 0; n0 < 8; n0++) {
            s8v bh = *(const s8v*)&Wch[(n0 * 16 + lid) * 40 + quad * 8];
            s8v bl = *(const s8v*)&Wch[5120 + (n0 * 16 + lid) * 40 + quad * 8];
            acc[n0] = __builtin_amdgcn_mfma_f32_16x16x32_bf16(ah, bh, acc[n0], 0, 0, 0);
            acc[n0] = __builtin_amdgcn_mfma_f32_16x16x32_bf16(al, bh, acc[n0], 0, 0, 0);
            acc[n0] = __builtin_amdgcn_mfma_f32_16x16x32_bf16(ah, bl, acc[n0], 0, 0, 0);
        }
        __syncthreads();
    }

    // ---- epilogue: bias, store, stats ----
    float* Sred = (float*)Wch;
#pragma unroll
    for (int n0 = 0; n0 < 8; n0++) {
        int c = n0 * 16 + lid;
        float bb = b2[c];
        float s = 0.f, q = 0.f;
#pragma unroll
        for (int rr = 0; rr < 4; rr++) {
            int grow = row0 + w * 16 + quad * 4 + rr;
            if (grow < NN) {
                float v = acc[n0][rr] + bb;
                C[(size_t)grow * 128 + c] = v;
                s += v;
                q += v * v;
            }
        }
        s += __shfl_xor(s, 16); s += __shfl_xor(s, 32);
        q += __shfl_xor(q, 16); q += __shfl_xor(q, 32);
        if (quad == 0) {
            Sred[w * 128 + c] = s;
            Sred[512 + w * 128 + c] = q;
        }
    }
    __syncthreads();
    if (tid < 128) {
        float s = Sred[tid] + Sred[128 + tid] + Sred[256 + tid] + Sred[384 + tid];
        float q = Sred[512 + tid] + Sred[640 + tid] + Sred[768 + tid] + Sred[896 + tid];
        atomicAdd(&stout[tid], s);
        atomicAdd(&stout[FF + tid], q);
    }
}

// ---------------- fused h1: agg(BN+relu on load) + double block-diag MLP -----------
// As/Ts use BSTR=20-float per-16-col blocks: k-block bank bases {0,20,8,28,16,4,24,12}
// -> conflict-free a/b fragment reads (R13 had 4-way, 3.2M conflicts).
__global__ __launch_bounds__(256) void k_aggbd(const float4* __restrict__ X,
                                               const int* __restrict__ offs,
                                               const int* __restrict__ csr,
                                               const float* __restrict__ st,
                                               const float* __restrict__ g,
                                               const float* __restrict__ be,
                                               const float* __restrict__ W1,
                                               const float4* __restrict__ b1,
                                               const float* __restrict__ W2,
                                               const float4* __restrict__ b2,
                                               float4* __restrict__ C) {
    __shared__ float As[8][8 * BSTR];
    __shared__ float Ts[8][8 * BSTR];
    __shared__ float Ws1[KF * KSTR];
    __shared__ float Ws2[KF * KSTR];
    int grp = threadIdx.x >> 5, lane = threadIdx.x & 31;
    int n = blockIdx.x * 8 + grp;

    for (int l = threadIdx.x; l < KF * 256; l += 256) {
        int k = l >> 8, r = l & 255;
        Ws1[k * KSTR + r] = W1[l];
        Ws2[k * KSTR + r] = W2[l];
    }

    float4 a4, b4;
    bn_coefs(st, g, be, lane, a4, b4);
    auto apply = [&](float4 v) -> float4 {
        v.x = fmaxf(fmaf(v.x, a4.x, b4.x), 0.f);
        v.y = fmaxf(fmaf(v.y, a4.y, b4.y), 0.f);
        v.z = fmaxf(fmaf(v.z, a4.z, b4.z), 0.f);
        v.w = fmaxf(fmaf(v.w, a4.w, b4.w), 0.f);
        return v;
    };
    auto add4 = [](float4& a, float4 b) {
        a.x += b.x; a.y += b.y; a.z += b.z; a.w += b.w;
    };

    float4 acc = apply(X[(size_t)n * 32 + lane]);
    int e0 = offs[n], e1 = offs[n + 1];
    int e = e0;
    for (; e + 8 <= e1; e += 8) {
        int s0 = csr[e], s1 = csr[e + 1], s2 = csr[e + 2], s3 = csr[e + 3];
        int s4 = csr[e + 4], s5 = csr[e + 5], s6 = csr[e + 6], s7 = csr[e + 7];
        float4 v0 = X[(size_t)s0 * 32 + lane];
        float4 v1 = X[(size_t)s1 * 32 + lane];
        float4 v2 = X[(size_t)s2 * 32 + lane];
        float4 v3 = X[(size_t)s3 * 32 + lane];
        float4 v4 = X[(size_t)s4 * 32 + lane];
        float4 v5 = X[(size_t)s5 * 32 + lane];
        float4 v6 = X[(size_t)s6 * 32 + lane];
        float4 v7 = X[(size_t)s7 * 32 + lane];
        v0 = apply(v0); v1 = apply(v1); v2 = apply(v2); v3 = apply(v3);
        v4 = apply(v4); v5 = apply(v5); v6 = apply(v6); v7 = apply(v7);
        add4(v0, v1); add4(v2, v3); add4(v4, v5); add4(v6, v7);
        add4(v0, v2); add4(v4, v6); add4(v0, v4); add4(acc, v0);
    }
    for (; e + 4 <= e1; e += 4) {
        int s0 = csr[e], s1 = csr[e + 1], s2 = csr[e + 2], s3 = csr[e + 3];
        float4 v0 = apply(X[(size_t)s0 * 32 + lane]);
        float4 v1 = apply(X[(size_t)s1 * 32 + lane]);
        float4 v2 = apply(X[(size_t)s2 * 32 + lane]);
        float4 v3 = apply(X[(size_t)s3 * 32 + lane]);
        add4(v0, v1); add4(v2, v3); add4(v0, v2); add4(acc, v0);
    }
    for (; e < e1; e++) {
        float4 v = apply(X[(size_t)csr[e] * 32 + lane]);
        add4(acc, v);
    }
    // store agg result (cols lane*4..+3) into padded layout
    *(float4*)&As[grp][(lane >> 2) * BSTR + (lane & 3) * 4] = acc;
    __syncthreads();

    int k = lane >> 2, jb = (lane & 3) * 4;
    float a[16];
    {
        const float4* As4 = (const float4*)&As[grp][k * BSTR];
        float4 a0 = As4[0], a1 = As4[1], a2 = As4[2], a3 = As4[3];
        a[0] = a0.x; a[1] = a0.y; a[2] = a0.z; a[3] = a0.w;
        a[4] = a1.x; a[5] = a1.y; a[6] = a1.z; a[7] = a1.w;
        a[8] = a2.x; a[9] = a2.y; a[10] = a2.z; a[11] = a2.w;
        a[12] = a3.x; a[13] = a3.y; a[14] = a3.z; a[15] = a3.w;
    }
    const float* wp1 = &Ws1[k * KSTR + jb];
    float4 t = b1[lane];
#pragma unroll
    for (int i = 0; i < 16; i++) {
        float4 wv = *(const float4*)&wp1[i * 16];
        t.x = fmaf(a[i], wv.x, t.x);
        t.y = fmaf(a[i], wv.y, t.y);
        t.z = fmaf(a[i], wv.z, t.z);
        t.w = fmaf(a[i], wv.w, t.w);
    }
    t.x = fmaxf(t.x, 0.f); t.y = fmaxf(t.y, 0.f);
    t.z = fmaxf(t.z, 0.f); t.w = fmaxf(t.w, 0.f);
    *(float4*)&Ts[grp][(lane >> 2) * BSTR + (lane & 3) * 4] = t;
    __syncthreads();

    float b[16];
    {
        const float4* Ts4 = (const float4*)&Ts[grp][k * BSTR];
        float4 a0 = Ts4[0], a1 = Ts4[1], a2 = Ts4[2], a3 = Ts4[3];
        b[0] = a0.x; b[1] = a0.y; b[2] = a0.z; b[3] = a0.w;
        b[4] = a1.x; b[5] = a1.y; b[6] = a1.z; b[7] = a1.w;
        b[8] = a2.x; b[9] = a2.y; b[10] = a2.z; b[11] = a2.w;
        b[12] = a3.x; b[13] = a3.y; b[14] = a3.z; b[15] = a3.w;
    }
    const float* wp2 = &Ws2[k * KSTR + jb];
    float4 acc2 = b2[lane];
#pragma unroll
    for (int i = 0; i < 16; i++) {
        float4 wv = *(const float4*)&wp2[i * 16];
        acc2.x = fmaf(b[i], wv.x, acc2.x);
        acc2.y = fmaf(b[i], wv.y, acc2.y);
        acc2.z = fmaf(b[i], wv.z, acc2.z);
        acc2.w = fmaf(b[i], wv.w, acc2.w);
    }
    C[(size_t)n * 32 + lane] = acc2;
}

// ---------------- BN stats (standalone, for k_aggbd output) ----------------
__global__ __launch_bounds__(256) void k_stats(const float* __restrict__ X,
                                               float* __restrict__ st, int nrows) {
    int c = threadIdx.x & 127;
    int half = threadIdx.x >> 7;
    int rpb = (nrows + gridDim.x - 1) / gridDim.x;
    int r0 = blockIdx.x * rpb;
    int r1 = min(r0 + rpb, nrows);
    float s = 0.f, sq = 0.f;
    for (int r = r0 + half; r < r1; r += 2) {
        float v = X[(size_t)r * FF + c];
        s += v;
        sq += v * v;
    }
    atomicAdd(&st[c], s);
    atomicAdd(&st[FF + c], sq);
}

// ---------------- pooling with fused final BN ----------------
__global__ __launch_bounds__(128) void k_pool(const float* __restrict__ X,
                                              const int* __restrict__ batch,
                                              const float* __restrict__ st,
                                              const float* __restrict__ g,
                                              const float* __restrict__ be,
                                              float* __restrict__ out) {
    int c = threadIdx.x;
    const float inv_n = 1.0f / (float)NN;
    float mu = st[c] * inv_n;
    float var = st[FF + c] * inv_n - mu * mu;
    float a = g[c] * rsqrtf(var + BN_EPS);
    float b = be[c] - mu * a;
    int chunk = (NN + gridDim.x - 1) / gridDim.x;
    int r0 = blockIdx.x * chunk;
    int r1 = min(r0 + chunk, NN);
    if (r0 >= r1) return;
    float acc = 0.f;
    int cnt = 0;
    int cur = batch[r0];
    for (int r = r0; r < r1; r++) {
        int bb = batch[r];
        if (bb != cur) {
            atomicAdd(&out[(size_t)cur * FF + c], fmaf(a, acc, b * (float)cnt));
            acc = 0.f;
            cnt = 0;
            cur = bb;
        }
        acc += X[(size_t)r * FF + c];
        cnt++;
    }
    atomicAdd(&out[(size_t)cur * FF + c], fmaf(a, acc, b * (float)cnt));
}

extern "C" void kernel_launch(void* const* d_in, const int* in_sizes, int n_in,
                              void* d_out, int out_size, void* d_ws, size_t ws_size,
                              hipStream_t stream) {
    const float* x = (const float*)d_in[0];
    const int* ei = (const int*)d_in[1];
    const int* src = ei;
    const int* dst = ei + NE;
    const int* batch = (const int*)d_in[2];
    const float* gc_W1 = (const float*)d_in[4];
    const float* gc_b1 = (const float*)d_in[5];
    const float* gc_W2 = (const float*)d_in[6];
    const float* gc_b2 = (const float*)d_in[7];
    const float* gc_g = (const float*)d_in[8];
    const float* gc_be = (const float*)d_in[9];
    const float* h0_W1 = (const float*)d_in[10];
    const float* h0_b1 = (const float*)d_in[11];
    const float* h0_W2 = (const float*)d_in[12];
    const float* h0_b2 = (const float*)d_in[13];
    const float* h0_g = (const float*)d_in[14];
    const float* h0_be = (const float*)d_in[15];
    const float* h1_W1 = (const float*)d_in[16];
    const float* h1_b1 = (const float*)d_in[17];
    const float* h1_W2 = (const float*)d_in[18];
    const float* h1_b2 = (const float*)d_in[19];
    const float* h1_g = (const float*)d_in[20];
    const float* h1_be = (const float*)d_in[21];

    const size_t NF = (size_t)NN * FF;
    float* P0 = (float*)d_ws;  // reused as two bf16 planes (Zhi, Zlo)
    float* P1 = P0 + NF;
    float* P2 = P1 + NF;
    float* stats = P2 + NF;
    int* deg = (int*)(stats + 5 * 256);
    int* cnt = deg + NN;
    int* offs = cnt + NN;
    int* bsum = offs + (NN + 4);
    int* boffs = bsum + 256;
    int* csr = boffs + 256;
    unsigned short* wbf = (unsigned short*)(csr + NE);  // 8 slots x 32768 shorts

    unsigned short* Zhi = (unsigned short*)P0;
    unsigned short* Zlo = Zhi + NF;

    hipMemsetAsync(deg, 0, (size_t)2 * NN * sizeof(int), stream);
    hipMemsetAsync(stats, 0, 5 * 256 * sizeof(float), stream);
    hipMemsetAsync(d_out, 0, (size_t)GG * KF * DD * sizeof(float), stream);

    k_deg<<<(NE + 255) / 256, 256, 0, stream>>>(dst, deg);
    k_bsum<<<NB, 256, 0, stream>>>(deg, bsum);
    k_bscan<<<1, 256, 0, stream>>>(bsum, boffs);
    k_offs<<<NB, 256, 0, stream>>>(deg, boffs, offs);
    k_fill<<<(NE + 255) / 256, 256, 0, stream>>>(src, dst, offs, cnt, csr);
    k_wprep<<<(3 * 2 * 16384 + 255) / 256, 256, 0, stream>>>(gc_W1, gc_W2, wbf);
    k_wprep_h0<<<(2 * 16384 + 255) / 256, 256, 0, stream>>>(h0_W1, h0_W2, wbf);

    const int agg_grid = NN / 8;            // 6250
    const int gemm_grid = (NN + 63) / 64;   // 782

    // ---- GC layers: agg(bf16-plane out) + MFMA bf16x3 gemm pair (stats fused) ----
    k_agg<false, false><<<agg_grid, 256, 0, stream>>>(
        (const float4*)x, offs, csr, nullptr, nullptr, nullptr, Zhi, Zlo);
    gemm_mfma<<<gemm_grid, 256, 0, stream>>>(
        Zhi, Zlo, wbf + 0 * 32768, wbf + 1 * 32768, gc_b1, gc_b2, P2, stats);

    k_agg<true, true><<<agg_grid, 256, 0, stream>>>(
        (const float4*)P2, offs, csr, stats, gc_g, gc_be, Zhi, Zlo);
    gemm_mfma<<<gemm_grid, 256, 0, stream>>>(
        Zhi, Zlo, wbf + 2 * 32768, wbf + 3 * 32768, gc_b1 + FF, gc_b2 + FF, P2, stats + 256);

    k_agg<true, true><<<agg_grid, 256, 0, stream>>>(
        (const float4*)P2, offs, csr, stats + 256, gc_g + FF, gc_be + FF, Zhi, Zlo);
    gemm_mfma<<<gemm_grid, 256, 0, stream>>>(
        Zhi, Zlo, wbf + 4 * 32768, wbf + 5 * 32768, gc_b1 + 2 * FF, gc_b2 + 2 * FF, P2, stats + 512);

    // ---- head layer 0: agg (GC2 BN, no relu) + MFMA (Wcat + blockdiag) ----
    k_agg<true, false><<<agg_grid, 256, 0, stream>>>(
        (const float4*)P2, offs, csr, stats + 512, gc_g + 2 * FF, gc_be + 2 * FF, Zhi, Zlo);
    gemm_mfma<<<gemm_grid, 256, 0, stream>>>(
        Zhi, Zlo, wbf + 6 * 32768, wbf + 7 * 32768, h0_b1, h0_b2, P1, stats + 768);

    // ---- head layer 1: fused agg(BN+relu) + double block-diag MLP ----
    k_aggbd<<<agg_grid, 256, 0, stream>>>(
        (const float4*)P1, offs, csr, stats + 768, h0_g, h0_be,
        h1_W1, (const float4*)h1_b1, h1_W2, (const float4*)h1_b2, (float4*)P2);
    k_stats<<<256, 256, 0, stream>>>(P2, stats + 1024, NN);

    // ---- pool with fused final BN ----
    k_pool<<<512, 128, 0, stream>>>(P2, batch, stats + 1024, h1_g, h1_be, (float*)d_out);
}